// Round 3
// baseline (389.065 us; speedup 1.0000x reference)
//
#include <hip/hip_runtime.h>
#include <hip/hip_bf16.h>

// MicroHeadAttention on MI355X (gfx950). Inputs fp32, output fp32 (confirmed by the
// round-2 dtype probe: low-16-bit halfwords of x are random mantissa bits -> fp32).
// Internally bf16 MFMA with fp32 accumulation.
// Pipeline: [fused QKV gemm fp32->bf16] -> [scrambled-head flash attention bf16] ->
//           [out-proj gemm bf16xfp32 -> fp32].
// Packed index i = n*8 + m per (b,g): scrambled head m'=i>>11, causal in i&2047 within head.
// Address of packed row i: (b*2048 + (i>>3))*1024 + g*512 + (i&7)*64.

typedef unsigned short ushortT;
typedef __attribute__((ext_vector_type(8))) short short8;
typedef __attribute__((ext_vector_type(4))) float floatx4;

__device__ inline float bf2f(ushortT u) {
    union { unsigned int i; float f; } v; v.i = ((unsigned int)u) << 16; return v.f;
}
__device__ inline ushortT f2bf(float f) {
    union { float f; unsigned int i; } v; v.f = f;
    unsigned int x = v.i;
    return (ushortT)((x + 0x7fffu + ((x >> 16) & 1u)) >> 16);  // RNE
}

// C[m, n] = sum_k A[m,k] * W[n,k] + bias[n]; A: M x 1024 row-major.
// W conceptually stacked (W0|W1|W2), each 1024x1024. 128x128 tile, 4 waves, 4x4 MFMA.
template <bool A_F32, bool W_F32, bool OUT_F32>
__global__ __launch_bounds__(256) void gemm_bt(
    const void* __restrict__ A,
    const void* __restrict__ W0, const void* __restrict__ W1, const void* __restrict__ W2,
    const void* __restrict__ b0, const void* __restrict__ b1, const void* __restrict__ b2,
    void* __restrict__ O0, void* __restrict__ O1, void* __restrict__ O2)
{
    __shared__ ushortT As[128 * 72];  // pad to 72 elts (144 B): aligned rows for ds_read_b128
    __shared__ ushortT Bs[128 * 72];
    const int t = threadIdx.x;
    const int m0 = blockIdx.y * 128;
    const int n0g = blockIdx.x * 128;
    const int mat = n0g >> 10;
    const int n0 = n0g & 1023;
    const void* W    = (mat == 0) ? W0 : (mat == 1) ? W1 : W2;
    const void* bias = (mat == 0) ? b0 : (mat == 1) ? b1 : b2;
    void* Out        = (mat == 0) ? O0 : (mat == 1) ? O1 : O2;

    const int w = t >> 6, lane = t & 63;
    const int wm = w >> 1, wn = w & 1;           // 2x2 wave grid, 64x64 per wave
    const int col16 = lane & 15, quad = lane >> 4;

    floatx4 acc[4][4];
    for (int i = 0; i < 4; i++)
        for (int j = 0; j < 4; j++) acc[i][j] = (floatx4)0.0f;

    const int srow = t >> 1, shalf = t & 1;      // 256 threads stage 128 rows x 64 cols

    for (int k0 = 0; k0 < 1024; k0 += 64) {
        // ---- stage A tile ----
        {
            const size_t off = (size_t)(m0 + srow) * 1024 + k0 + shalf * 32;
            ushortT* dA = As + srow * 72 + shalf * 32;
            if constexpr (A_F32) {
                const float4* src = (const float4*)((const float*)A + off);
                #pragma unroll
                for (int e = 0; e < 8; e++) {
                    float4 f = src[e];
                    dA[e * 4 + 0] = f2bf(f.x); dA[e * 4 + 1] = f2bf(f.y);
                    dA[e * 4 + 2] = f2bf(f.z); dA[e * 4 + 3] = f2bf(f.w);
                }
            } else {
                const uint4* src = (const uint4*)((const ushortT*)A + off);
                uint4* dst = (uint4*)dA;
                dst[0] = src[0]; dst[1] = src[1]; dst[2] = src[2]; dst[3] = src[3];
            }
        }
        // ---- stage W tile ----
        {
            const size_t off = (size_t)(n0 + srow) * 1024 + k0 + shalf * 32;
            ushortT* dB = Bs + srow * 72 + shalf * 32;
            if constexpr (W_F32) {
                const float4* src = (const float4*)((const float*)W + off);
                #pragma unroll
                for (int e = 0; e < 8; e++) {
                    float4 f = src[e];
                    dB[e * 4 + 0] = f2bf(f.x); dB[e * 4 + 1] = f2bf(f.y);
                    dB[e * 4 + 2] = f2bf(f.z); dB[e * 4 + 3] = f2bf(f.w);
                }
            } else {
                const uint4* src = (const uint4*)((const ushortT*)W + off);
                uint4* dst = (uint4*)dB;
                dst[0] = src[0]; dst[1] = src[1]; dst[2] = src[2]; dst[3] = src[3];
            }
        }
        __syncthreads();
        for (int ks = 0; ks < 64; ks += 32) {
            short8 a[4], b[4];
            for (int i = 0; i < 4; i++)
                a[i] = *(const short8*)(As + (wm * 64 + i * 16 + col16) * 72 + ks + quad * 8);
            for (int j = 0; j < 4; j++)
                b[j] = *(const short8*)(Bs + (wn * 64 + j * 16 + col16) * 72 + ks + quad * 8);
            for (int i = 0; i < 4; i++)
                for (int j = 0; j < 4; j++)
                    acc[i][j] = __builtin_amdgcn_mfma_f32_16x16x32_bf16(a[i], b[j], acc[i][j], 0, 0, 0);
        }
        __syncthreads();
    }

    for (int j = 0; j < 4; j++) {
        const int colg = n0 + wn * 64 + j * 16 + col16;
        const float bv = W_F32 ? ((const float*)bias)[colg] : bf2f(((const ushortT*)bias)[colg]);
        for (int i = 0; i < 4; i++) {
            const int rbase = m0 + wm * 64 + i * 16 + quad * 4;
            for (int r = 0; r < 4; r++) {
                const float val = acc[i][j][r] + bv;
                if constexpr (OUT_F32)
                    ((float*)Out)[(size_t)(rbase + r) * 1024 + colg] = val;
                else
                    ((ushortT*)Out)[(size_t)(rbase + r) * 1024 + colg] = f2bf(val);
            }
        }
    }
}

// Flash attention over packed/scrambled heads (bf16 in workspace).
// grid: 1024 blocks = b(2) * g(2) * mh'(8) * qtile(32). Block = 256 threads (4 waves),
// each wave owns 16 query rows of the 64-row q-tile. Bc = 64 keys per iteration.
// Cb may alias Qb: each block stages its own 64 Q rows up-front and writes the same
// 64 rows as C at the end; no cross-block Q sharing.
__global__ __launch_bounds__(256) void attn(
    const ushortT* __restrict__ Qb, const ushortT* __restrict__ Kb,
    const ushortT* __restrict__ Vb, ushortT* __restrict__ Cb)
{
    __shared__ ushortT Qs[64 * 72];
    __shared__ ushortT Ks[64 * 72];
    __shared__ ushortT Vt[64 * 72];  // transposed: Vt[d][key]
    __shared__ ushortT Ps[64 * 72];

    const int t = threadIdx.x;
    const int bid = blockIdx.x;
    const int qt = bid & 31;
    const int mh = (bid >> 5) & 7;
    const int g  = (bid >> 8) & 1;
    const int bb = bid >> 9;

    const int w = t >> 6, lane = t & 63;
    const int col16 = lane & 15, quad = lane >> 4;

    const size_t baseoff = (size_t)bb * 2048 * 1024 + (size_t)g * 512;
    const int i0 = mh * 2048 + qt * 64;

    // stage Q tile (64 rows x 64 d)
    {
        const int row = t >> 2, seg = t & 3;
        const int i = i0 + row;
        const uint4* src = (const uint4*)(Qb + baseoff + (size_t)(i >> 3) * 1024 + (i & 7) * 64 + seg * 16);
        uint4* dst = (uint4*)(Qs + row * 72 + seg * 16);
        dst[0] = src[0]; dst[1] = src[1];
    }

    float m_r[4] = {-1e30f, -1e30f, -1e30f, -1e30f};
    float l_r[4] = {0.f, 0.f, 0.f, 0.f};
    floatx4 Oacc[4];
    for (int c = 0; c < 4; c++) Oacc[c] = (floatx4)0.0f;
    const float scale = 0.125f;  // dh^-0.5

    for (int kt = 0; kt <= qt; ++kt) {
        // stage K tile, V tile (V transposed into Vt[d][key])
        {
            const int row = t >> 2, seg = t & 3;
            const int j = mh * 2048 + kt * 64 + row;
            const size_t go = baseoff + (size_t)(j >> 3) * 1024 + (j & 7) * 64 + seg * 16;
            const uint4* srcK = (const uint4*)(Kb + go);
            uint4* dstK = (uint4*)(Ks + row * 72 + seg * 16);
            dstK[0] = srcK[0]; dstK[1] = srcK[1];
            union { uint4 u[2]; ushortT s[16]; } vtmp;
            const uint4* srcV = (const uint4*)(Vb + go);
            vtmp.u[0] = srcV[0]; vtmp.u[1] = srcV[1];
            for (int d = 0; d < 16; ++d)
                Vt[(seg * 16 + d) * 72 + row] = vtmp.s[d];
        }
        __syncthreads();

        // S = Q K^T for this wave's 16 rows x 64 keys
        floatx4 s[4];
        for (int c = 0; c < 4; c++) s[c] = (floatx4)0.0f;
        for (int ks = 0; ks < 64; ks += 32) {
            const short8 a = *(const short8*)(Qs + (w * 16 + col16) * 72 + ks + quad * 8);
            for (int c = 0; c < 4; c++) {
                const short8 b = *(const short8*)(Ks + (c * 16 + col16) * 72 + ks + quad * 8);
                s[c] = __builtin_amdgcn_mfma_f32_16x16x32_bf16(a, b, s[c], 0, 0, 0);
            }
        }

        // scale + causal mask (diagonal tile only) + online softmax
        const bool diag = (kt == qt);
        float p[4][4];
        for (int r = 0; r < 4; r++) {
            const int rloc = w * 16 + quad * 4 + r;
            float mx = -1e30f;
            for (int c = 0; c < 4; c++) {
                float sv = s[c][r] * scale;
                if (diag && (c * 16 + col16) > rloc) sv = -1e30f;
                p[c][r] = sv;
                mx = fmaxf(mx, sv);
            }
            mx = fmaxf(mx, __shfl_xor(mx, 1));
            mx = fmaxf(mx, __shfl_xor(mx, 2));
            mx = fmaxf(mx, __shfl_xor(mx, 4));
            mx = fmaxf(mx, __shfl_xor(mx, 8));
            const float mnew = fmaxf(m_r[r], mx);
            const float alpha = __expf(m_r[r] - mnew);
            m_r[r] = mnew;
            float sum = 0.f;
            for (int c = 0; c < 4; c++) {
                const float pv = __expf(p[c][r] - mnew);
                p[c][r] = pv;
                sum += pv;
            }
            sum += __shfl_xor(sum, 1);
            sum += __shfl_xor(sum, 2);
            sum += __shfl_xor(sum, 4);
            sum += __shfl_xor(sum, 8);
            l_r[r] = l_r[r] * alpha + sum;
            for (int c = 0; c < 4; c++) Oacc[c][r] *= alpha;
        }

        // P -> LDS (bf16, A-operand reload)
        for (int c = 0; c < 4; c++)
            for (int r = 0; r < 4; r++)
                Ps[(w * 16 + quad * 4 + r) * 72 + c * 16 + col16] = f2bf(p[c][r]);
        __syncthreads();

        // O += P @ V
        for (int kk = 0; kk < 64; kk += 32) {
            const short8 a = *(const short8*)(Ps + (w * 16 + col16) * 72 + kk + quad * 8);
            for (int c = 0; c < 4; c++) {
                const short8 b = *(const short8*)(Vt + (c * 16 + col16) * 72 + kk + quad * 8);
                Oacc[c] = __builtin_amdgcn_mfma_f32_16x16x32_bf16(a, b, Oacc[c], 0, 0, 0);
            }
        }
        __syncthreads();
    }

    // write ctx rows (same packed addressing as Q)
    for (int r = 0; r < 4; r++) {
        const int i = i0 + w * 16 + quad * 4 + r;
        const float inv = 1.0f / l_r[r];
        ushortT* dst = Cb + baseoff + (size_t)(i >> 3) * 1024 + (i & 7) * 64;
        for (int c = 0; c < 4; c++)
            dst[c * 16 + col16] = f2bf(Oacc[c][r] * inv);
    }
}

extern "C" void kernel_launch(void* const* d_in, const int* in_sizes, int n_in,
                              void* d_out, int out_size, void* d_ws, size_t ws_size,
                              hipStream_t stream)
{
    const void* x  = d_in[0];
    const void* Wq = d_in[1];
    const void* bq = d_in[2];
    const void* Wk = d_in[3];
    const void* bk = d_in[4];
    const void* Wv = d_in[5];
    const void* bv = d_in[6];
    const void* Wo = d_in[7];
    const void* bo = d_in[8];

    ushortT* Qb = (ushortT*)d_ws;                 // 4096x1024 bf16 = 8 MB
    ushortT* Kb = Qb + (size_t)4096 * 1024;
    ushortT* Vb = Kb + (size_t)4096 * 1024;
    ushortT* Cb = Qb;                              // alias (safe: per-block row ownership)

    dim3 blk(256);
    // fused QKV projection: 4096 x 3072 x 1024, fp32 in -> bf16 out
    gemm_bt<true, true, false><<<dim3(24, 32), blk, 0, stream>>>(
        x, Wq, Wk, Wv, bq, bk, bv, Qb, Kb, Vb);
    // scrambled-head causal flash attention (bf16)
    attn<<<dim3(1024), blk, 0, stream>>>(Qb, Kb, Vb, Cb);
    // output projection: 4096 x 1024 x 1024, bf16 A x fp32 W -> fp32 out
    gemm_bt<false, true, true><<<dim3(8, 32), blk, 0, stream>>>(
        Cb, Wo, Wo, Wo, bo, bo, bo, d_out, d_out, d_out);
}

// Round 4
// 300.108 us; speedup vs baseline: 1.2964x; 1.2964x over previous
//
#include <hip/hip_runtime.h>
#include <hip/hip_bf16.h>

// MicroHeadAttention on MI355X (gfx950). fp32 in / fp32 out, bf16 MFMA internally.
// Pipeline: [fused QKV gemm (packed-cvt staging)] -> [transpose_v] ->
//           [pair-balanced scrambled-head flash attention] -> [out-proj gemm].
// Packed index i = n*8 + m per (b,g): scrambled head m'=i>>11, pos = i&2047.
// Address of packed row i: (b*2048 + (i>>3))*1024 + g*512 + (i&7)*64.

typedef unsigned short ushortT;
typedef __attribute__((ext_vector_type(8))) short short8;
typedef __attribute__((ext_vector_type(4))) float floatx4;

__device__ inline float bf2f(ushortT u) {
    union { unsigned int i; float f; } v; v.i = ((unsigned int)u) << 16; return v.f;
}
__device__ inline ushortT f2bf(float f) {
    union { float f; unsigned int i; } v; v.f = f;
    unsigned int x = v.i;
    return (ushortT)((x + 0x7fffu + ((x >> 16) & 1u)) >> 16);  // RNE
}

// ---------------------------------------------------------------------------
// GEMM: C[m,n] = sum_k A[m,k] * W[n,k] + bias[n]; A: M x 1024 row-major.
// W stacked (W0|W1|W2) each 1024x1024. 128x128 tile, 4 waves, 4x4 MFMA.
// fp32 operands are converted to bf16 during LDS staging via packed hw cvt.
// ---------------------------------------------------------------------------
template <bool A_F32, bool W_F32, bool OUT_F32>
__global__ __launch_bounds__(256) void gemm_bt(
    const void* __restrict__ A,
    const void* __restrict__ W0, const void* __restrict__ W1, const void* __restrict__ W2,
    const void* __restrict__ b0, const void* __restrict__ b1, const void* __restrict__ b2,
    void* __restrict__ O0, void* __restrict__ O1, void* __restrict__ O2)
{
    __shared__ ushortT As[128 * 72];
    __shared__ ushortT Bs[128 * 72];
    const int t = threadIdx.x;
    const int m0 = blockIdx.y * 128;
    const int n0g = blockIdx.x * 128;
    const int mat = n0g >> 10;
    const int n0 = n0g & 1023;
    const void* W    = (mat == 0) ? W0 : (mat == 1) ? W1 : W2;
    const void* bias = (mat == 0) ? b0 : (mat == 1) ? b1 : b2;
    void* Out        = (mat == 0) ? O0 : (mat == 1) ? O1 : O2;

    const int w = t >> 6, lane = t & 63;
    const int wm = w >> 1, wn = w & 1;
    const int col16 = lane & 15, quad = lane >> 4;

    floatx4 acc[4][4];
    for (int i = 0; i < 4; i++)
        for (int j = 0; j < 4; j++) acc[i][j] = (floatx4)0.0f;

    const int srow = t >> 1, shalf = t & 1;

    for (int k0 = 0; k0 < 1024; k0 += 64) {
        {
            const size_t off = (size_t)(m0 + srow) * 1024 + k0 + shalf * 32;
            ushortT* dA = As + srow * 72 + shalf * 32;
            if constexpr (A_F32) {
                const float4* src = (const float4*)((const float*)A + off);
                __hip_bfloat162* d2 = (__hip_bfloat162*)dA;
                #pragma unroll
                for (int e = 0; e < 8; e++) {
                    float4 f = src[e];
                    d2[e * 2 + 0] = __float22bfloat162_rn(float2{f.x, f.y});
                    d2[e * 2 + 1] = __float22bfloat162_rn(float2{f.z, f.w});
                }
            } else {
                const uint4* src = (const uint4*)((const ushortT*)A + off);
                uint4* dst = (uint4*)dA;
                dst[0] = src[0]; dst[1] = src[1]; dst[2] = src[2]; dst[3] = src[3];
            }
        }
        {
            const size_t off = (size_t)(n0 + srow) * 1024 + k0 + shalf * 32;
            ushortT* dB = Bs + srow * 72 + shalf * 32;
            if constexpr (W_F32) {
                const float4* src = (const float4*)((const float*)W + off);
                __hip_bfloat162* d2 = (__hip_bfloat162*)dB;
                #pragma unroll
                for (int e = 0; e < 8; e++) {
                    float4 f = src[e];
                    d2[e * 2 + 0] = __float22bfloat162_rn(float2{f.x, f.y});
                    d2[e * 2 + 1] = __float22bfloat162_rn(float2{f.z, f.w});
                }
            } else {
                const uint4* src = (const uint4*)((const ushortT*)W + off);
                uint4* dst = (uint4*)dB;
                dst[0] = src[0]; dst[1] = src[1]; dst[2] = src[2]; dst[3] = src[3];
            }
        }
        __syncthreads();
        for (int ks = 0; ks < 64; ks += 32) {
            short8 a[4], b[4];
            for (int i = 0; i < 4; i++)
                a[i] = *(const short8*)(As + (wm * 64 + i * 16 + col16) * 72 + ks + quad * 8);
            for (int j = 0; j < 4; j++)
                b[j] = *(const short8*)(Bs + (wn * 64 + j * 16 + col16) * 72 + ks + quad * 8);
            for (int i = 0; i < 4; i++)
                for (int j = 0; j < 4; j++)
                    acc[i][j] = __builtin_amdgcn_mfma_f32_16x16x32_bf16(a[i], b[j], acc[i][j], 0, 0, 0);
        }
        __syncthreads();
    }

    for (int j = 0; j < 4; j++) {
        const int colg = n0 + wn * 64 + j * 16 + col16;
        const float bv = W_F32 ? ((const float*)bias)[colg] : bf2f(((const ushortT*)bias)[colg]);
        for (int i = 0; i < 4; i++) {
            const int rbase = m0 + wm * 64 + i * 16 + quad * 4;
            for (int r = 0; r < 4; r++) {
                const float val = acc[i][j][r] + bv;
                if constexpr (OUT_F32)
                    ((float*)Out)[(size_t)(rbase + r) * 1024 + colg] = val;
                else
                    ((ushortT*)Out)[(size_t)(rbase + r) * 1024 + colg] = f2bf(val);
            }
        }
    }
}

// ---------------------------------------------------------------------------
// transpose_v: Vb (packed rows) -> VT[slice][d (64)][pos (2048)], slice = (b*2+g)*8+m'.
// 1024 blocks = 32 slices x 32 pos-tiles of 64. LDS 64x65 pad kills write/read conflicts.
// ---------------------------------------------------------------------------
__global__ __launch_bounds__(256) void transpose_v(
    const ushortT* __restrict__ Vb, ushortT* __restrict__ VT)
{
    __shared__ ushortT L[64 * 65];
    const int bid = blockIdx.x;
    const int pt = bid & 31, s = bid >> 5;
    const int bb = s >> 4, g = (s >> 3) & 1, mh = s & 7;
    const size_t baseoff = (size_t)bb * 2048 * 1024 + (size_t)g * 512;
    const int t = threadIdx.x;
    {
        const int pr = t >> 2, seg = t & 3;
        const int i = mh * 2048 + pt * 64 + pr;
        const uint4* src = (const uint4*)(Vb + baseoff + (size_t)(i >> 3) * 1024 + (i & 7) * 64 + seg * 16);
        union { uint4 u[2]; ushortT h[16]; } tmp;
        tmp.u[0] = src[0]; tmp.u[1] = src[1];
        #pragma unroll
        for (int d = 0; d < 16; d++) L[pr * 65 + seg * 16 + d] = tmp.h[d];
    }
    __syncthreads();
    {
        const int dc = t >> 2, pseg = t & 3;
        union { uint4 u[2]; ushortT h[16]; } tmp;
        #pragma unroll
        for (int j = 0; j < 16; j++) tmp.h[j] = L[(pseg * 16 + j) * 65 + dc];
        uint4* dst = (uint4*)(VT + (size_t)s * 64 * 2048 + (size_t)dc * 2048 + pt * 64 + pseg * 16);
        dst[0] = tmp.u[0]; dst[1] = tmp.u[1];
    }
}

// ---------------------------------------------------------------------------
// attn v2: pair-balanced flash attention. 512 blocks = 32 slices x 16 pairs.
// Each block owns q-tiles qtA=p and qtB=31-p (64 rows each) -> exactly 33
// compute-iterations per block. 4 waves; wave w owns rows [w*16,+16) of BOTH
// tiles. K/V^T staged per kt; Ps is per-wave private (no barrier around it).
// Cb may alias Qb (block writes only the rows it staged).
// ---------------------------------------------------------------------------
__global__ __launch_bounds__(256) void attn(
    const ushortT* __restrict__ Qb, const ushortT* __restrict__ Kb,
    const ushortT* __restrict__ VT, ushortT* __restrict__ Cb)
{
    __shared__ ushortT Qs[128 * 72];  // rows 0..63 = tile A, 64..127 = tile B
    __shared__ ushortT Ks[64 * 72];
    __shared__ ushortT Vs[64 * 72];   // Vs[d][key] straight from VT
    __shared__ ushortT Ps[64 * 72];   // per-wave private 16-row slabs (reused A then B)

    const int t = threadIdx.x;
    const int bid = blockIdx.x;
    const int s = bid >> 4;
    const int pidx = bid & 15;
    const int p = (s & 16) ? (15 - pidx) : pidx;   // balances staging-length across CUs
    const int qtA = p, qtB = 31 - p;               // compute work: (p+1)+(32-p)=33 iters
    const int bb = s >> 4, g = (s >> 3) & 1, mh = s & 7;

    const int w = t >> 6, lane = t & 63;
    const int col16 = lane & 15, quad = lane >> 4;

    const size_t baseoff = (size_t)bb * 2048 * 1024 + (size_t)g * 512;
    const size_t vtbase  = (size_t)s * 64 * 2048;
    const int i0A = mh * 2048 + qtA * 64;
    const int i0B = mh * 2048 + qtB * 64;

    // stage both Q tiles (128 rows x 64 d)
    {
        const int row = t >> 1, half = t & 1;      // row 0..127
        const int i = ((row < 64) ? i0A : i0B) + (row & 63);
        const uint4* src = (const uint4*)(Qb + baseoff + (size_t)(i >> 3) * 1024 + (i & 7) * 64 + half * 32);
        uint4* dst = (uint4*)(Qs + row * 72 + half * 32);
        dst[0] = src[0]; dst[1] = src[1]; dst[2] = src[2]; dst[3] = src[3];
    }

    float mA[4], lA[4], mB[4], lB[4];
    floatx4 OA[4], OB[4];
    for (int r = 0; r < 4; r++) { mA[r] = -1e30f; lA[r] = 0.f; mB[r] = -1e30f; lB[r] = 0.f; }
    for (int c = 0; c < 4; c++) { OA[c] = (floatx4)0.0f; OB[c] = (floatx4)0.0f; }
    const float scale = 0.125f;

    const int ktmax = qtB;  // qtB >= qtA always
    for (int kt = 0; kt <= ktmax; ++kt) {
        // stage K tile and V^T tile
        {
            const int row = t >> 2, seg = t & 3;
            const int j = mh * 2048 + kt * 64 + row;
            const uint4* srcK = (const uint4*)(Kb + baseoff + (size_t)(j >> 3) * 1024 + (j & 7) * 64 + seg * 16);
            uint4* dstK = (uint4*)(Ks + row * 72 + seg * 16);
            dstK[0] = srcK[0]; dstK[1] = srcK[1];
            const uint4* srcV = (const uint4*)(VT + vtbase + (size_t)row * 2048 + kt * 64 + seg * 16);
            uint4* dstV = (uint4*)(Vs + row * 72 + seg * 16);
            dstV[0] = srcV[0]; dstV[1] = srcV[1];
        }
        __syncthreads();

        #pragma unroll
        for (int tile = 0; tile < 2; ++tile) {
            const int qt = tile ? qtB : qtA;
            if (kt > qt) continue;                 // wave-uniform
            float* m_r = tile ? mB : mA;
            float* l_r = tile ? lB : lA;
            floatx4* Oacc = tile ? OB : OA;
            const int qsoff = tile ? 64 * 72 : 0;

            // S = Q K^T (16 rows x 64 keys per wave)
            floatx4 sc[4];
            for (int c = 0; c < 4; c++) sc[c] = (floatx4)0.0f;
            for (int ks = 0; ks < 64; ks += 32) {
                const short8 a = *(const short8*)(Qs + qsoff + (w * 16 + col16) * 72 + ks + quad * 8);
                for (int c = 0; c < 4; c++) {
                    const short8 b = *(const short8*)(Ks + (c * 16 + col16) * 72 + ks + quad * 8);
                    sc[c] = __builtin_amdgcn_mfma_f32_16x16x32_bf16(a, b, sc[c], 0, 0, 0);
                }
            }

            // scale + causal mask (diag tile) + online softmax
            const bool diag = (kt == qt);
            float pr[4][4];
            for (int r = 0; r < 4; r++) {
                const int rloc = w * 16 + quad * 4 + r;
                float mx = -1e30f;
                for (int c = 0; c < 4; c++) {
                    float sv = sc[c][r] * scale;
                    if (diag && (c * 16 + col16) > rloc) sv = -1e30f;
                    pr[c][r] = sv;
                    mx = fmaxf(mx, sv);
                }
                mx = fmaxf(mx, __shfl_xor(mx, 1));
                mx = fmaxf(mx, __shfl_xor(mx, 2));
                mx = fmaxf(mx, __shfl_xor(mx, 4));
                mx = fmaxf(mx, __shfl_xor(mx, 8));
                const float mnew = fmaxf(m_r[r], mx);
                const float alpha = __expf(m_r[r] - mnew);
                m_r[r] = mnew;
                float sum = 0.f;
                for (int c = 0; c < 4; c++) {
                    const float pv = __expf(pr[c][r] - mnew);
                    pr[c][r] = pv;
                    sum += pv;
                }
                sum += __shfl_xor(sum, 1);
                sum += __shfl_xor(sum, 2);
                sum += __shfl_xor(sum, 4);
                sum += __shfl_xor(sum, 8);
                l_r[r] = l_r[r] * alpha + sum;
                for (int c = 0; c < 4; c++) Oacc[c][r] *= alpha;
            }

            // P -> per-wave-private LDS slab (A-operand reload; no block barrier needed)
            for (int c = 0; c < 4; c++)
                for (int r = 0; r < 4; r++)
                    Ps[(w * 16 + quad * 4 + r) * 72 + c * 16 + col16] = f2bf(pr[c][r]);

            // O += P @ V  (B operand rows are Vs[d][*])
            for (int kk = 0; kk < 64; kk += 32) {
                const short8 a = *(const short8*)(Ps + (w * 16 + col16) * 72 + kk + quad * 8);
                for (int c = 0; c < 4; c++) {
                    const short8 b = *(const short8*)(Vs + (c * 16 + col16) * 72 + kk + quad * 8);
                    Oacc[c] = __builtin_amdgcn_mfma_f32_16x16x32_bf16(a, b, Oacc[c], 0, 0, 0);
                }
            }
        }
        __syncthreads();
    }

    // write ctx rows for both tiles (same packed addressing as Q)
    for (int tile = 0; tile < 2; ++tile) {
        const int i0 = tile ? i0B : i0A;
        float* l_r = tile ? lB : lA;
        floatx4* Oacc = tile ? OB : OA;
        for (int r = 0; r < 4; r++) {
            const int i = i0 + w * 16 + quad * 4 + r;
            const float inv = 1.0f / l_r[r];
            ushortT* dst = Cb + baseoff + (size_t)(i >> 3) * 1024 + (i & 7) * 64;
            for (int c = 0; c < 4; c++)
                dst[c * 16 + col16] = f2bf(Oacc[c][r] * inv);
        }
    }
}

extern "C" void kernel_launch(void* const* d_in, const int* in_sizes, int n_in,
                              void* d_out, int out_size, void* d_ws, size_t ws_size,
                              hipStream_t stream)
{
    const void* x  = d_in[0];
    const void* Wq = d_in[1];
    const void* bq = d_in[2];
    const void* Wk = d_in[3];
    const void* bk = d_in[4];
    const void* Wv = d_in[5];
    const void* bv = d_in[6];
    const void* Wo = d_in[7];
    const void* bo = d_in[8];

    ushortT* Qb  = (ushortT*)d_ws;                   // 8 MB
    ushortT* Kb  = Qb + (size_t)4096 * 1024;         // 8 MB
    ushortT* Vb  = Kb + (size_t)4096 * 1024;         // 8 MB
    ushortT* VTb = Vb + (size_t)4096 * 1024;         // 8 MB (V^T per slice)
    ushortT* Cb  = Qb;                               // alias (per-block row ownership)

    dim3 blk(256);
    gemm_bt<true, true, false><<<dim3(24, 32), blk, 0, stream>>>(
        x, Wq, Wk, Wv, bq, bk, bv, Qb, Kb, Vb);
    transpose_v<<<dim3(1024), blk, 0, stream>>>(Vb, VTb);
    attn<<<dim3(512), blk, 0, stream>>>(Qb, Kb, VTb, Cb);
    gemm_bt<false, true, true><<<dim3(8, 32), blk, 0, stream>>>(
        Cb, Wo, Wo, Wo, bo, bo, bo, d_out, d_out, d_out);
}

// Round 5
// 235.641 us; speedup vs baseline: 1.6511x; 1.2736x over previous
//
#include <hip/hip_runtime.h>
#include <hip/hip_bf16.h>

// MicroHeadAttention on MI355X (gfx950). fp32 in / fp32 out, bf16 MFMA internally.
// Pipeline: [cvt fp32->bf16: x, Wq|Wk|Wv|Wo] -> [QKV gemm, global_load_lds staging]
//        -> [transpose_v] -> [pair-balanced flash attention] -> [out-proj gemm].
// Packed index i = n*8 + m per (b,g): scrambled head m'=i>>11, pos = i&2047.
// Address of packed row i: (b*2048 + (i>>3))*1024 + g*512 + (i&7)*64.
// Workspace (32 MB): Wb(8) | xb(8, reused as VT after QKV) | Qb(8, reused as Cb) | Kb(8).
// V lives in d_out as scratch (dead before out-proj overwrites d_out).

typedef unsigned short ushortT;
typedef __attribute__((ext_vector_type(8))) short short8;
typedef __attribute__((ext_vector_type(4))) float floatx4;

__device__ inline float bf2f(ushortT u) {
    union { unsigned int i; float f; } v; v.i = ((unsigned int)u) << 16; return v.f;
}
__device__ inline ushortT f2bf(float f) {
    union { float f; unsigned int i; } v; v.f = f;
    unsigned int x = v.i;
    return (ushortT)((x + 0x7fffu + ((x >> 16) & 1u)) >> 16);  // RNE
}

// async global->LDS, 16 B per lane; LDS dest is wave-uniform base + lane*16.
__device__ inline void gl_lds16(const ushortT* g, ushortT* lds) {
    __builtin_amdgcn_global_load_lds(
        (const __attribute__((address_space(1))) unsigned int*)g,
        (__attribute__((address_space(3))) unsigned int*)lds, 16, 0, 0);
}

// ---------------------------------------------------------------------------
// cvt: x (4M f32) -> xb bf16; Wq,Wk,Wv,Wo (1M each) -> Wb stacked bf16.
// 1M threads x 8 elements. Regions are 1M-element aligned.
// ---------------------------------------------------------------------------
__global__ __launch_bounds__(256) void cvt_bf16(
    const float* __restrict__ x,
    const float* __restrict__ Wq, const float* __restrict__ Wk,
    const float* __restrict__ Wv, const float* __restrict__ Wo,
    ushortT* __restrict__ xb, ushortT* __restrict__ Wb)
{
    const unsigned tid = blockIdx.x * 256 + threadIdx.x;
    const size_t e = (size_t)tid * 8;
    const float* src;
    ushortT* dst;
    size_t off;
    if (e < (size_t)(4u << 20)) { src = x; dst = xb; off = e; }
    else {
        const size_t r = e - (size_t)(4u << 20);
        const int wsel = (int)(r >> 20);
        off = r & 0xFFFFFu;
        src = (wsel == 0) ? Wq : (wsel == 1) ? Wk : (wsel == 2) ? Wv : Wo;
        dst = Wb + ((size_t)wsel << 20);
    }
    const float4 f0 = ((const float4*)(src + off))[0];
    const float4 f1 = ((const float4*)(src + off))[1];
    union { __hip_bfloat162 h[4]; uint4 u; } pk;
    pk.h[0] = __float22bfloat162_rn(float2{f0.x, f0.y});
    pk.h[1] = __float22bfloat162_rn(float2{f0.z, f0.w});
    pk.h[2] = __float22bfloat162_rn(float2{f1.x, f1.y});
    pk.h[3] = __float22bfloat162_rn(float2{f1.z, f1.w});
    *(uint4*)(dst + off) = pk.u;
}

// ---------------------------------------------------------------------------
// gemm_lds: C[m,n] = sum_k A[m,k]*W[n,k] + bias[n]. Pure bf16 operands, m97-style
// global_load_lds staging (16 B/lane) with XOR chunk swizzle (chunk ^= row&7):
// LDS stays lane-contiguous (required by global_load_lds) AND ds_read_b128 is
// conflict-free (rows 0..7 cover all 8 chunk slots -> all 32 banks, 2-way = free).
// 128x128 tile, BK=64, 4 waves 2x2, 4x4 mfma_f32_16x16x32_bf16 per wave.
// W stacked (up to 3 mats of 1024x1024); bias fp32.
// ---------------------------------------------------------------------------
template <bool OUT_F32>
__global__ __launch_bounds__(256) void gemm_lds(
    const ushortT* __restrict__ A, const ushortT* __restrict__ Wst,
    const float* __restrict__ b0, const float* __restrict__ b1, const float* __restrict__ b2,
    void* __restrict__ O0, void* __restrict__ O1, void* __restrict__ O2)
{
    __shared__ ushortT As[128 * 64];   // 16 KB, unpadded (global_load_lds layout)
    __shared__ ushortT Bs[128 * 64];
    const int t = threadIdx.x;
    const int m0 = blockIdx.y * 128;
    const int n0g = blockIdx.x * 128;
    const int mat = n0g >> 10;
    const int n0 = n0g & 1023;
    const ushortT* W = Wst + ((size_t)mat << 20);
    const float* bias = (mat == 0) ? b0 : (mat == 1) ? b1 : b2;
    void* Out        = (mat == 0) ? O0 : (mat == 1) ? O1 : O2;

    const int w = t >> 6, lane = t & 63;
    const int wm = w >> 1, wn = w & 1;
    const int col16 = lane & 15, quad = lane >> 4;

    floatx4 acc[4][4];
    for (int i = 0; i < 4; i++)
        for (int j = 0; j < 4; j++) acc[i][j] = (floatx4)0.0f;

    // staging: chunk id cid = w*256 + q*64 + lane; row = cid>>3, chunk = cid&7,
    // source chunk = chunk ^ (row & 7). Dest = contiguous chunk cid.
    const int cid0 = w * 256 + lane;

    for (int k0 = 0; k0 < 1024; k0 += 64) {
        #pragma unroll
        for (int q = 0; q < 4; q++) {
            const int cid = cid0 + q * 64;
            const int row = cid >> 3;
            const int sch = (cid & 7) ^ (row & 7);
            ushortT* dstA = As + (size_t)(w * 256 + q * 64) * 8;   // wave-uniform
            ushortT* dstB = Bs + (size_t)(w * 256 + q * 64) * 8;
            gl_lds16(A + (size_t)(m0 + row) * 1024 + k0 + sch * 8, dstA);
            gl_lds16(W + (size_t)(n0 + row) * 1024 + k0 + sch * 8, dstB);
        }
        __syncthreads();
        #pragma unroll
        for (int ks = 0; ks < 64; ks += 32) {
            const int cbase = (ks >> 3) + quad;
            const int sw = col16 & 7;           // == row & 7 for all fragment rows
            short8 a[4], b[4];
            #pragma unroll
            for (int i = 0; i < 4; i++) {
                const int row = wm * 64 + i * 16 + col16;
                a[i] = *(const short8*)(As + row * 64 + ((cbase ^ sw) << 3));
            }
            #pragma unroll
            for (int j = 0; j < 4; j++) {
                const int row = wn * 64 + j * 16 + col16;
                b[j] = *(const short8*)(Bs + row * 64 + ((cbase ^ sw) << 3));
            }
            #pragma unroll
            for (int i = 0; i < 4; i++)
                #pragma unroll
                for (int j = 0; j < 4; j++)
                    acc[i][j] = __builtin_amdgcn_mfma_f32_16x16x32_bf16(a[i], b[j], acc[i][j], 0, 0, 0);
        }
        __syncthreads();
    }

    for (int j = 0; j < 4; j++) {
        const int colg = n0 + wn * 64 + j * 16 + col16;
        const float bv = bias[colg];
        for (int i = 0; i < 4; i++) {
            const int rbase = m0 + wm * 64 + i * 16 + quad * 4;
            for (int r = 0; r < 4; r++) {
                const float val = acc[i][j][r] + bv;
                if constexpr (OUT_F32)
                    ((float*)Out)[(size_t)(rbase + r) * 1024 + colg] = val;
                else
                    ((ushortT*)Out)[(size_t)(rbase + r) * 1024 + colg] = f2bf(val);
            }
        }
    }
}

// ---------------------------------------------------------------------------
// transpose_v: Vb (packed rows) -> VT[slice][d (64)][pos (2048)], slice=(b*2+g)*8+m'.
// 1024 blocks = 32 slices x 32 pos-tiles of 64. LDS 64x65 pad kills conflicts.
// ---------------------------------------------------------------------------
__global__ __launch_bounds__(256) void transpose_v(
    const ushortT* __restrict__ Vb, ushortT* __restrict__ VT)
{
    __shared__ ushortT L[64 * 65];
    const int bid = blockIdx.x;
    const int pt = bid & 31, s = bid >> 5;
    const int bb = s >> 4, g = (s >> 3) & 1, mh = s & 7;
    const size_t baseoff = (size_t)bb * 2048 * 1024 + (size_t)g * 512;
    const int t = threadIdx.x;
    {
        const int pr = t >> 2, seg = t & 3;
        const int i = mh * 2048 + pt * 64 + pr;
        const uint4* src = (const uint4*)(Vb + baseoff + (size_t)(i >> 3) * 1024 + (i & 7) * 64 + seg * 16);
        union { uint4 u[2]; ushortT h[16]; } tmp;
        tmp.u[0] = src[0]; tmp.u[1] = src[1];
        #pragma unroll
        for (int d = 0; d < 16; d++) L[pr * 65 + seg * 16 + d] = tmp.h[d];
    }
    __syncthreads();
    {
        const int dc = t >> 2, pseg = t & 3;
        union { uint4 u[2]; ushortT h[16]; } tmp;
        #pragma unroll
        for (int j = 0; j < 16; j++) tmp.h[j] = L[(pseg * 16 + j) * 65 + dc];
        uint4* dst = (uint4*)(VT + (size_t)s * 64 * 2048 + (size_t)dc * 2048 + pt * 64 + pseg * 16);
        dst[0] = tmp.u[0]; dst[1] = tmp.u[1];
    }
}

// ---------------------------------------------------------------------------
// attn: pair-balanced flash attention. 512 blocks = 32 slices x 16 pairs.
// Each block owns q-tiles qtA=p, qtB=31-p -> exactly 33 compute-iterations.
// 4 waves; wave w owns rows [w*16,+16) of both tiles. Ps is per-wave private.
// Cb may alias Qb (block writes only the rows it staged).
// ---------------------------------------------------------------------------
__global__ __launch_bounds__(256) void attn(
    const ushortT* __restrict__ Qb, const ushortT* __restrict__ Kb,
    const ushortT* __restrict__ VT, ushortT* __restrict__ Cb)
{
    __shared__ ushortT Qs[128 * 72];
    __shared__ ushortT Ks[64 * 72];
    __shared__ ushortT Vs[64 * 72];
    __shared__ ushortT Ps[64 * 72];

    const int t = threadIdx.x;
    const int bid = blockIdx.x;
    const int s = bid >> 4;
    const int pidx = bid & 15;
    const int p = (s & 16) ? (15 - pidx) : pidx;
    const int qtA = p, qtB = 31 - p;
    const int bb = s >> 4, g = (s >> 3) & 1, mh = s & 7;

    const int w = t >> 6, lane = t & 63;
    const int col16 = lane & 15, quad = lane >> 4;

    const size_t baseoff = (size_t)bb * 2048 * 1024 + (size_t)g * 512;
    const size_t vtbase  = (size_t)s * 64 * 2048;
    const int i0A = mh * 2048 + qtA * 64;
    const int i0B = mh * 2048 + qtB * 64;

    {
        const int row = t >> 1, half = t & 1;
        const int i = ((row < 64) ? i0A : i0B) + (row & 63);
        const uint4* src = (const uint4*)(Qb + baseoff + (size_t)(i >> 3) * 1024 + (i & 7) * 64 + half * 32);
        uint4* dst = (uint4*)(Qs + row * 72 + half * 32);
        dst[0] = src[0]; dst[1] = src[1]; dst[2] = src[2]; dst[3] = src[3];
    }

    float mA[4], lA[4], mB[4], lB[4];
    floatx4 OA[4], OB[4];
    for (int r = 0; r < 4; r++) { mA[r] = -1e30f; lA[r] = 0.f; mB[r] = -1e30f; lB[r] = 0.f; }
    for (int c = 0; c < 4; c++) { OA[c] = (floatx4)0.0f; OB[c] = (floatx4)0.0f; }
    const float scale = 0.125f;

    const int ktmax = qtB;
    for (int kt = 0; kt <= ktmax; ++kt) {
        {
            const int row = t >> 2, seg = t & 3;
            const int j = mh * 2048 + kt * 64 + row;
            const uint4* srcK = (const uint4*)(Kb + baseoff + (size_t)(j >> 3) * 1024 + (j & 7) * 64 + seg * 16);
            uint4* dstK = (uint4*)(Ks + row * 72 + seg * 16);
            dstK[0] = srcK[0]; dstK[1] = srcK[1];
            const uint4* srcV = (const uint4*)(VT + vtbase + (size_t)row * 2048 + kt * 64 + seg * 16);
            uint4* dstV = (uint4*)(Vs + row * 72 + seg * 16);
            dstV[0] = srcV[0]; dstV[1] = srcV[1];
        }
        __syncthreads();

        #pragma unroll
        for (int tile = 0; tile < 2; ++tile) {
            const int qt = tile ? qtB : qtA;
            if (kt > qt) continue;
            float* m_r = tile ? mB : mA;
            float* l_r = tile ? lB : lA;
            floatx4* Oacc = tile ? OB : OA;
            const int qsoff = tile ? 64 * 72 : 0;

            floatx4 sc[4];
            for (int c = 0; c < 4; c++) sc[c] = (floatx4)0.0f;
            for (int ks = 0; ks < 64; ks += 32) {
                const short8 a = *(const short8*)(Qs + qsoff + (w * 16 + col16) * 72 + ks + quad * 8);
                for (int c = 0; c < 4; c++) {
                    const short8 b = *(const short8*)(Ks + (c * 16 + col16) * 72 + ks + quad * 8);
                    sc[c] = __builtin_amdgcn_mfma_f32_16x16x32_bf16(a, b, sc[c], 0, 0, 0);
                }
            }

            const bool diag = (kt == qt);
            float pr[4][4];
            for (int r = 0; r < 4; r++) {
                const int rloc = w * 16 + quad * 4 + r;
                float mx = -1e30f;
                for (int c = 0; c < 4; c++) {
                    float sv = sc[c][r] * scale;
                    if (diag && (c * 16 + col16) > rloc) sv = -1e30f;
                    pr[c][r] = sv;
                    mx = fmaxf(mx, sv);
                }
                mx = fmaxf(mx, __shfl_xor(mx, 1));
                mx = fmaxf(mx, __shfl_xor(mx, 2));
                mx = fmaxf(mx, __shfl_xor(mx, 4));
                mx = fmaxf(mx, __shfl_xor(mx, 8));
                const float mnew = fmaxf(m_r[r], mx);
                const float alpha = __expf(m_r[r] - mnew);
                m_r[r] = mnew;
                float sum = 0.f;
                for (int c = 0; c < 4; c++) {
                    const float pv = __expf(pr[c][r] - mnew);
                    pr[c][r] = pv;
                    sum += pv;
                }
                sum += __shfl_xor(sum, 1);
                sum += __shfl_xor(sum, 2);
                sum += __shfl_xor(sum, 4);
                sum += __shfl_xor(sum, 8);
                l_r[r] = l_r[r] * alpha + sum;
                for (int c = 0; c < 4; c++) Oacc[c][r] *= alpha;
            }

            for (int c = 0; c < 4; c++)
                for (int r = 0; r < 4; r++)
                    Ps[(w * 16 + quad * 4 + r) * 72 + c * 16 + col16] = f2bf(pr[c][r]);

            for (int kk = 0; kk < 64; kk += 32) {
                const short8 a = *(const short8*)(Ps + (w * 16 + col16) * 72 + kk + quad * 8);
                for (int c = 0; c < 4; c++) {
                    const short8 b = *(const short8*)(Vs + (c * 16 + col16) * 72 + kk + quad * 8);
                    Oacc[c] = __builtin_amdgcn_mfma_f32_16x16x32_bf16(a, b, Oacc[c], 0, 0, 0);
                }
            }
        }
        __syncthreads();
    }

    for (int tile = 0; tile < 2; ++tile) {
        const int i0 = tile ? i0B : i0A;
        float* l_r = tile ? lB : lA;
        floatx4* Oacc = tile ? OB : OA;
        for (int r = 0; r < 4; r++) {
            const int i = i0 + w * 16 + quad * 4 + r;
            const float inv = 1.0f / l_r[r];
            ushortT* dst = Cb + baseoff + (size_t)(i >> 3) * 1024 + (i & 7) * 64;
            for (int c = 0; c < 4; c++)
                dst[c * 16 + col16] = f2bf(Oacc[c][r] * inv);
        }
    }
}

extern "C" void kernel_launch(void* const* d_in, const int* in_sizes, int n_in,
                              void* d_out, int out_size, void* d_ws, size_t ws_size,
                              hipStream_t stream)
{
    const float* x  = (const float*)d_in[0];
    const float* Wq = (const float*)d_in[1];
    const float* bq = (const float*)d_in[2];
    const float* Wk = (const float*)d_in[3];
    const float* bk = (const float*)d_in[4];
    const float* Wv = (const float*)d_in[5];
    const float* bv = (const float*)d_in[6];
    const float* Wo = (const float*)d_in[7];
    const float* bo = (const float*)d_in[8];

    const size_t M1 = (size_t)1024 * 1024;
    ushortT* Wb  = (ushortT*)d_ws;            // 4M elts (Wq|Wk|Wv|Wo bf16), 8 MB
    ushortT* xb  = Wb + 4 * M1;               // 4M elts, 8 MB; reused as VT after QKV
    ushortT* Qb  = xb + 4 * M1;               // 8 MB; reused as Cb
    ushortT* Kb  = Qb + 4 * M1;               // 8 MB  (total 32 MB)
    ushortT* Vb  = (ushortT*)d_out;           // scratch inside output buffer (16 MB avail)
    ushortT* VTb = xb;
    ushortT* Cb  = Qb;

    dim3 blk(256);
    cvt_bf16<<<dim3(4096), blk, 0, stream>>>(x, Wq, Wk, Wv, Wo, xb, Wb);
    // QKV: 4096 x 3072 x 1024, bf16 -> bf16 (V into d_out scratch)
    gemm_lds<false><<<dim3(24, 32), blk, 0, stream>>>(
        xb, Wb, bq, bk, bv, Qb, Kb, Vb);
    transpose_v<<<dim3(1024), blk, 0, stream>>>(Vb, VTb);
    attn<<<dim3(512), blk, 0, stream>>>(Qb, Kb, VTb, Cb);
    // out-proj: 4096 x 1024 x 1024, bf16 -> fp32 (overwrites V scratch)
    gemm_lds<true><<<dim3(8, 32), blk, 0, stream>>>(
        Cb, Wb + 3 * M1, bo, bo, bo, d_out, d_out, d_out);
}

// Round 6
// 218.748 us; speedup vs baseline: 1.7786x; 1.0772x over previous
//
#include <hip/hip_runtime.h>
#include <hip/hip_bf16.h>

// MicroHeadAttention on MI355X (gfx950). fp32 in / fp32 out, bf16 MFMA internally.
// Pipeline: [cvt fp32->bf16] -> [QKV gemm, global_load_lds] -> [transpose_v]
//        -> [attn v3: transposed-softmax, XCD-swizzled, dbuf gl_lds staging] -> [out-proj gemm].
// Packed index i = n*8 + m per (b,g): scrambled head m'=i>>11, pos = i&2047.
// Address of packed row i: (b*2048 + (i>>3))*1024 + g*512 + (i&7)*64.
// Workspace (32 MB): Wb(8) | xb(8, reused as VT) | Qb(8, reused as Cb) | Kb(8).
// V uses d_out as scratch (dead before out-proj overwrites d_out).

typedef unsigned short ushortT;
typedef __attribute__((ext_vector_type(8))) short short8;
typedef __attribute__((ext_vector_type(4))) float floatx4;

__device__ inline float bf2f(ushortT u) {
    union { unsigned int i; float f; } v; v.i = ((unsigned int)u) << 16; return v.f;
}
__device__ inline ushortT f2bf(float f) {
    union { float f; unsigned int i; } v; v.f = f;
    unsigned int x = v.i;
    return (ushortT)((x + 0x7fffu + ((x >> 16) & 1u)) >> 16);  // RNE
}

__device__ inline void gl_lds16(const ushortT* g, ushortT* lds) {
    __builtin_amdgcn_global_load_lds(
        (const __attribute__((address_space(1))) unsigned int*)g,
        (__attribute__((address_space(3))) unsigned int*)lds, 16, 0, 0);
}

// ---------------------------------------------------------------------------
// cvt: x (4M f32) -> xb bf16; Wq,Wk,Wv,Wo (1M each) -> Wb stacked bf16.
// ---------------------------------------------------------------------------
__global__ __launch_bounds__(256) void cvt_bf16(
    const float* __restrict__ x,
    const float* __restrict__ Wq, const float* __restrict__ Wk,
    const float* __restrict__ Wv, const float* __restrict__ Wo,
    ushortT* __restrict__ xb, ushortT* __restrict__ Wb)
{
    const unsigned tid = blockIdx.x * 256 + threadIdx.x;
    const size_t e = (size_t)tid * 8;
    const float* src;
    ushortT* dst;
    size_t off;
    if (e < (size_t)(4u << 20)) { src = x; dst = xb; off = e; }
    else {
        const size_t r = e - (size_t)(4u << 20);
        const int wsel = (int)(r >> 20);
        off = r & 0xFFFFFu;
        src = (wsel == 0) ? Wq : (wsel == 1) ? Wk : (wsel == 2) ? Wv : Wo;
        dst = Wb + ((size_t)wsel << 20);
    }
    const float4 f0 = ((const float4*)(src + off))[0];
    const float4 f1 = ((const float4*)(src + off))[1];
    union { __hip_bfloat162 h[4]; uint4 u; } pk;
    pk.h[0] = __float22bfloat162_rn(float2{f0.x, f0.y});
    pk.h[1] = __float22bfloat162_rn(float2{f0.z, f0.w});
    pk.h[2] = __float22bfloat162_rn(float2{f1.x, f1.y});
    pk.h[3] = __float22bfloat162_rn(float2{f1.z, f1.w});
    *(uint4*)(dst + off) = pk.u;
}

// ---------------------------------------------------------------------------
// gemm_lds: C[m,n] = sum_k A[m,k]*W[n,k] + bias[n]. Pure bf16, global_load_lds
// staging with XOR chunk swizzle. 128x128 tile, BK=64, 4 waves, 4x4 MFMA.
// ---------------------------------------------------------------------------
template <bool OUT_F32>
__global__ __launch_bounds__(256) void gemm_lds(
    const ushortT* __restrict__ A, const ushortT* __restrict__ Wst,
    const float* __restrict__ b0, const float* __restrict__ b1, const float* __restrict__ b2,
    void* __restrict__ O0, void* __restrict__ O1, void* __restrict__ O2)
{
    __shared__ __align__(16) ushortT As[128 * 64];
    __shared__ __align__(16) ushortT Bs[128 * 64];
    const int t = threadIdx.x;
    const int m0 = blockIdx.y * 128;
    const int n0g = blockIdx.x * 128;
    const int mat = n0g >> 10;
    const int n0 = n0g & 1023;
    const ushortT* W = Wst + ((size_t)mat << 20);
    const float* bias = (mat == 0) ? b0 : (mat == 1) ? b1 : b2;
    void* Out        = (mat == 0) ? O0 : (mat == 1) ? O1 : O2;

    const int w = t >> 6, lane = t & 63;
    const int wm = w >> 1, wn = w & 1;
    const int col16 = lane & 15, quad = lane >> 4;

    floatx4 acc[4][4];
    for (int i = 0; i < 4; i++)
        for (int j = 0; j < 4; j++) acc[i][j] = (floatx4)0.0f;

    const int cid0 = w * 256 + lane;

    for (int k0 = 0; k0 < 1024; k0 += 64) {
        #pragma unroll
        for (int q = 0; q < 4; q++) {
            const int cid = cid0 + q * 64;
            const int row = cid >> 3;
            const int sch = (cid & 7) ^ (row & 7);
            ushortT* dstA = As + (size_t)(w * 256 + q * 64) * 8;
            ushortT* dstB = Bs + (size_t)(w * 256 + q * 64) * 8;
            gl_lds16(A + (size_t)(m0 + row) * 1024 + k0 + sch * 8, dstA);
            gl_lds16(W + (size_t)(n0 + row) * 1024 + k0 + sch * 8, dstB);
        }
        __syncthreads();
        #pragma unroll
        for (int ks = 0; ks < 64; ks += 32) {
            const int cbase = (ks >> 3) + quad;
            const int sw = col16 & 7;
            short8 a[4], b[4];
            #pragma unroll
            for (int i = 0; i < 4; i++) {
                const int row = wm * 64 + i * 16 + col16;
                a[i] = *(const short8*)(As + row * 64 + ((cbase ^ sw) << 3));
            }
            #pragma unroll
            for (int j = 0; j < 4; j++) {
                const int row = wn * 64 + j * 16 + col16;
                b[j] = *(const short8*)(Bs + row * 64 + ((cbase ^ sw) << 3));
            }
            #pragma unroll
            for (int i = 0; i < 4; i++)
                #pragma unroll
                for (int j = 0; j < 4; j++)
                    acc[i][j] = __builtin_amdgcn_mfma_f32_16x16x32_bf16(a[i], b[j], acc[i][j], 0, 0, 0);
        }
        __syncthreads();
    }

    for (int j = 0; j < 4; j++) {
        const int colg = n0 + wn * 64 + j * 16 + col16;
        const float bv = bias[colg];
        for (int i = 0; i < 4; i++) {
            const int rbase = m0 + wm * 64 + i * 16 + quad * 4;
            for (int r = 0; r < 4; r++) {
                const float val = acc[i][j][r] + bv;
                if constexpr (OUT_F32)
                    ((float*)Out)[(size_t)(rbase + r) * 1024 + colg] = val;
                else
                    ((ushortT*)Out)[(size_t)(rbase + r) * 1024 + colg] = f2bf(val);
            }
        }
    }
}

// ---------------------------------------------------------------------------
// transpose_v: Vb (packed rows) -> VT[slice][d (64)][pos (2048)], slice=(b*2+g)*8+m'.
// ---------------------------------------------------------------------------
__global__ __launch_bounds__(256) void transpose_v(
    const ushortT* __restrict__ Vb, ushortT* __restrict__ VT)
{
    __shared__ ushortT L[64 * 65];
    const int bid = blockIdx.x;
    const int pt = bid & 31, s = bid >> 5;
    const int bb = s >> 4, g = (s >> 3) & 1, mh = s & 7;
    const size_t baseoff = (size_t)bb * 2048 * 1024 + (size_t)g * 512;
    const int t = threadIdx.x;
    {
        const int pr = t >> 2, seg = t & 3;
        const int i = mh * 2048 + pt * 64 + pr;
        const uint4* src = (const uint4*)(Vb + baseoff + (size_t)(i >> 3) * 1024 + (i & 7) * 64 + seg * 16);
        union { uint4 u[2]; ushortT h[16]; } tmp;
        tmp.u[0] = src[0]; tmp.u[1] = src[1];
        #pragma unroll
        for (int d = 0; d < 16; d++) L[pr * 65 + seg * 16 + d] = tmp.h[d];
    }
    __syncthreads();
    {
        const int dc = t >> 2, pseg = t & 3;
        union { uint4 u[2]; ushortT h[16]; } tmp;
        #pragma unroll
        for (int j = 0; j < 16; j++) tmp.h[j] = L[(pseg * 16 + j) * 65 + dc];
        uint4* dst = (uint4*)(VT + (size_t)s * 64 * 2048 + (size_t)dc * 2048 + pt * 64 + pseg * 16);
        dst[0] = tmp.u[0]; dst[1] = tmp.u[1];
    }
}

// ---------------------------------------------------------------------------
// attn v3: transposed-softmax flash attention, XCD-aware, gl_lds double-buffered.
// 512 blocks: xcd=bid&7 gets 4 whole slices (K/V^T stay in one XCD L2).
// Each block: q-tiles qtA=p, qtB=31-p -> 33 compute-iterations. 4 waves; wave w
// owns q rows [w*16,+16) of both tiles, ONE query per lane (q = w*16 + col16).
// S^T = MFMA(A=K, B=Q): queries on col=lane&15 -> softmax row-reduce is
// 16 in-reg ops + 2 shuffles; m/l/alpha are per-lane scalars.
// O^T = MFMA(A=V^T, B=P^T): alpha-rescale and 1/l also per-lane scalar.
// Cb may alias Qb (block writes only rows it staged).
// ---------------------------------------------------------------------------
__global__ __launch_bounds__(256) void attn(
    const ushortT* __restrict__ Qb, const ushortT* __restrict__ Kb,
    const ushortT* __restrict__ VT, ushortT* __restrict__ Cb)
{
    __shared__ __align__(16) ushortT Qs[128 * 72];
    __shared__ __align__(16) ushortT Ks[2][64 * 64];   // [key][d], chunk-swizzled
    __shared__ __align__(16) ushortT Vs[2][64 * 64];   // [d][key], chunk-swizzled
    __shared__ __align__(16) ushortT Ps[64 * 72];      // [q][key], per-wave rows

    const int t = threadIdx.x;
    const int bid = blockIdx.x;
    const int xcd = bid & 7;
    const int jj  = bid >> 3;              // 0..63
    const int s   = xcd * 4 + (jj >> 4);   // slice 0..31, 4 slices per XCD
    const int p   = jj & 15;
    const int qtA = p, qtB = 31 - p;       // (p+1)+(32-p) = 33 iters, balanced
    const int bb = s >> 4, g = (s >> 3) & 1, mh = s & 7;

    const int w = t >> 6, lane = t & 63;
    const int col16 = lane & 15, quad = lane >> 4;

    const size_t baseoff = (size_t)bb * 2048 * 1024 + (size_t)g * 512;
    const size_t vtbase  = (size_t)s * 64 * 2048;
    const int i0A = mh * 2048 + qtA * 64;
    const int i0B = mh * 2048 + qtB * 64;
    const int qloc = w * 16 + col16;       // this lane's query row within a tile
    const float KL = 0.125f * 1.44269504f; // scale * log2(e), folded into exp2

    // stage both Q tiles (128 rows x 64 d), padded rows
    {
        const int row = t >> 1, half = t & 1;
        const int i = ((row < 64) ? i0A : i0B) + (row & 63);
        const uint4* src = (const uint4*)(Qb + baseoff + (size_t)(i >> 3) * 1024 + (i & 7) * 64 + half * 32);
        uint4* dst = (uint4*)(Qs + row * 72 + half * 32);
        dst[0] = src[0]; dst[1] = src[1]; dst[2] = src[2]; dst[3] = src[3];
    }

    // async K/V^T staging: 512 chunks of 16 B per tile, wave-uniform dests
    auto stageKV = [&](int kt, int bsel) {
        ushortT* kd = &Ks[bsel][0] + (size_t)(w * 128) * 8;
        ushortT* vd = &Vs[bsel][0] + (size_t)(w * 128) * 8;
        #pragma unroll
        for (int q = 0; q < 2; q++) {
            const int cid = w * 128 + q * 64 + lane;
            const int row = cid >> 3;
            const int sch = (cid & 7) ^ (row & 7);
            const int jr = mh * 2048 + kt * 64 + row;
            gl_lds16(Kb + baseoff + (size_t)(jr >> 3) * 1024 + (jr & 7) * 64 + sch * 8,
                     kd + q * 64 * 8);
            gl_lds16(VT + vtbase + (size_t)row * 2048 + kt * 64 + sch * 8,
                     vd + q * 64 * 8);
        }
    };

    float m_s[2] = {-1e30f, -1e30f};
    float l_s[2] = {0.f, 0.f};
    floatx4 Oacc[2][4];
    for (int tl = 0; tl < 2; tl++)
        for (int c = 0; c < 4; c++) Oacc[tl][c] = (floatx4)0.0f;

    stageKV(0, 0);
    const int ktmax = qtB;
    for (int kt = 0; kt <= ktmax; ++kt) {
        const int bsel = kt & 1;
        __syncthreads();                       // drains vmcnt -> buffers ready
        if (kt < ktmax) stageKV(kt + 1, bsel ^ 1);  // prefetch overlaps compute

        #pragma unroll
        for (int tile = 0; tile < 2; ++tile) {
            const int qt = tile ? qtB : qtA;
            if (kt > qt) continue;             // wave-uniform
            const int qsrow = (tile ? 64 : 0) + qloc;

            // S^T = K * Q^T : rows = keys, cols = queries (col16 = this lane's q)
            floatx4 sc[4];
            for (int c = 0; c < 4; c++) sc[c] = (floatx4)0.0f;
            #pragma unroll
            for (int ks = 0; ks < 64; ks += 32) {
                const short8 bq = *(const short8*)(Qs + qsrow * 72 + ks + quad * 8);
                #pragma unroll
                for (int c = 0; c < 4; c++) {
                    const int krow = c * 16 + col16;
                    const short8 ak = *(const short8*)(&Ks[bsel][0] + krow * 64 +
                                        ((((ks >> 3) + quad) ^ (krow & 7)) << 3));
                    sc[c] = __builtin_amdgcn_mfma_f32_16x16x32_bf16(ak, bq, sc[c], 0, 0, 0);
                }
            }

            // online softmax: lane holds 16 keys of ONE query
            const bool diag = (kt == qt);
            float mx = -1e30f;
            #pragma unroll
            for (int c = 0; c < 4; c++)
                #pragma unroll
                for (int r = 0; r < 4; r++) {
                    float v = sc[c][r];
                    if (diag && (c * 16 + quad * 4 + r) > qloc) v = -1e30f;
                    sc[c][r] = v;
                    mx = fmaxf(mx, v);
                }
            mx = fmaxf(mx, __shfl_xor(mx, 16));
            mx = fmaxf(mx, __shfl_xor(mx, 32));
            const float mold = m_s[tile];
            const float mnew = fmaxf(mold, mx);
            const float alpha = exp2f((mold - mnew) * KL);
            m_s[tile] = mnew;
            float sum = 0.f;
            #pragma unroll
            for (int c = 0; c < 4; c++)
                #pragma unroll
                for (int r = 0; r < 4; r++) {
                    const float pv = exp2f((sc[c][r] - mnew) * KL);
                    sc[c][r] = pv;
                    sum += pv;
                }
            sum += __shfl_xor(sum, 16);
            sum += __shfl_xor(sum, 32);
            l_s[tile] = l_s[tile] * alpha + sum;
            #pragma unroll
            for (int c = 0; c < 4; c++) Oacc[tile][c] *= alpha;

            // P -> Ps[q][key] (bf16 pairs); per-wave-private rows, no barrier
            #pragma unroll
            for (int c = 0; c < 4; c++)
                #pragma unroll
                for (int rp = 0; rp < 2; rp++) {
                    union { ushortT h[2]; unsigned int u; } pk;
                    pk.h[0] = f2bf(sc[c][rp * 2]);
                    pk.h[1] = f2bf(sc[c][rp * 2 + 1]);
                    *(unsigned int*)(Ps + qloc * 72 + c * 16 + quad * 4 + rp * 2) = pk.u;
                }

            // O^T += V^T * P^T : rows = d, cols = queries (same col16 = q)
            #pragma unroll
            for (int kk = 0; kk < 64; kk += 32) {
                const short8 bp = *(const short8*)(Ps + qloc * 72 + kk + quad * 8);
                #pragma unroll
                for (int c = 0; c < 4; c++) {
                    const int drow = c * 16 + col16;
                    const short8 av = *(const short8*)(&Vs[bsel][0] + drow * 64 +
                                        ((((kk >> 3) + quad) ^ (drow & 7)) << 3));
                    Oacc[tile][c] = __builtin_amdgcn_mfma_f32_16x16x32_bf16(av, bp, Oacc[tile][c], 0, 0, 0);
                }
            }
        }
    }

    // write ctx: lane owns query qloc of each tile, d = c*16 + quad*4 + r
    #pragma unroll
    for (int tile = 0; tile < 2; ++tile) {
        const int i = (tile ? i0B : i0A) + qloc;
        const float inv = 1.0f / l_s[tile];
        ushortT* dst = Cb + baseoff + (size_t)(i >> 3) * 1024 + (i & 7) * 64;
        #pragma unroll
        for (int c = 0; c < 4; c++)
            #pragma unroll
            for (int rp = 0; rp < 2; rp++) {
                union { ushortT h[2]; unsigned int u; } pk;
                pk.h[0] = f2bf(Oacc[tile][c][rp * 2] * inv);
                pk.h[1] = f2bf(Oacc[tile][c][rp * 2 + 1] * inv);
                *(unsigned int*)(dst + c * 16 + quad * 4 + rp * 2) = pk.u;
            }
    }
}

extern "C" void kernel_launch(void* const* d_in, const int* in_sizes, int n_in,
                              void* d_out, int out_size, void* d_ws, size_t ws_size,
                              hipStream_t stream)
{
    const float* x  = (const float*)d_in[0];
    const float* Wq = (const float*)d_in[1];
    const float* bq = (const float*)d_in[2];
    const float* Wk = (const float*)d_in[3];
    const float* bk = (const float*)d_in[4];
    const float* Wv = (const float*)d_in[5];
    const float* bv = (const float*)d_in[6];
    const float* Wo = (const float*)d_in[7];
    const float* bo = (const float*)d_in[8];

    const size_t M1 = (size_t)1024 * 1024;
    ushortT* Wb  = (ushortT*)d_ws;            // Wq|Wk|Wv|Wo bf16, 8 MB
    ushortT* xb  = Wb + 4 * M1;               // 8 MB; reused as VT after QKV
    ushortT* Qb  = xb + 4 * M1;               // 8 MB; reused as Cb
    ushortT* Kb  = Qb + 4 * M1;               // 8 MB
    ushortT* Vb  = (ushortT*)d_out;           // scratch in output buffer
    ushortT* VTb = xb;
    ushortT* Cb  = Qb;

    dim3 blk(256);
    cvt_bf16<<<dim3(4096), blk, 0, stream>>>(x, Wq, Wk, Wv, Wo, xb, Wb);
    gemm_lds<false><<<dim3(24, 32), blk, 0, stream>>>(
        xb, Wb, bq, bk, bv, Qb, Kb, Vb);
    transpose_v<<<dim3(1024), blk, 0, stream>>>(Vb, VTb);
    attn<<<dim3(512), blk, 0, stream>>>(Qb, Kb, VTb, Cb);
    gemm_lds<true><<<dim3(8, 32), blk, 0, stream>>>(
        Cb, Wb + 3 * M1, bo, bo, bo, d_out, d_out, d_out);
}

// Round 7
// 216.667 us; speedup vs baseline: 1.7957x; 1.0096x over previous
//
#include <hip/hip_runtime.h>
#include <hip/hip_bf16.h>

// MicroHeadAttention on MI355X (gfx950). fp32 in / fp32 out, bf16 MFMA internally.
// Pipeline: [cvt fp32->bf16] -> [QKV gemm, global_load_lds] -> [transpose_v]
//        -> [attn v4: Q-in-regs, 40KB LDS (4 blocks/CU), packed cvt] -> [out-proj gemm].
// Packed index i = n*8 + m per (b,g): scrambled head m'=i>>11, pos = i&2047.
// Address of packed row i: (b*2048 + (i>>3))*1024 + g*512 + (i&7)*64.
// Workspace (32 MB): Wb(8) | xb(8, reused as VT) | Qb(8, reused as Cb) | Kb(8).
// V uses d_out as scratch (dead before out-proj overwrites d_out).

typedef unsigned short ushortT;
typedef __attribute__((ext_vector_type(8))) short short8;
typedef __attribute__((ext_vector_type(4))) float floatx4;

__device__ inline float bf2f(ushortT u) {
    union { unsigned int i; float f; } v; v.i = ((unsigned int)u) << 16; return v.f;
}
__device__ inline ushortT f2bf(float f) {
    union { float f; unsigned int i; } v; v.f = f;
    unsigned int x = v.i;
    return (ushortT)((x + 0x7fffu + ((x >> 16) & 1u)) >> 16);  // RNE
}

__device__ inline void gl_lds16(const ushortT* g, ushortT* lds) {
    __builtin_amdgcn_global_load_lds(
        (const __attribute__((address_space(1))) unsigned int*)g,
        (__attribute__((address_space(3))) unsigned int*)lds, 16, 0, 0);
}

// ---------------------------------------------------------------------------
// cvt: x (4M f32) -> xb bf16; Wq,Wk,Wv,Wo (1M each) -> Wb stacked bf16.
// ---------------------------------------------------------------------------
__global__ __launch_bounds__(256) void cvt_bf16(
    const float* __restrict__ x,
    const float* __restrict__ Wq, const float* __restrict__ Wk,
    const float* __restrict__ Wv, const float* __restrict__ Wo,
    ushortT* __restrict__ xb, ushortT* __restrict__ Wb)
{
    const unsigned tid = blockIdx.x * 256 + threadIdx.x;
    const size_t e = (size_t)tid * 8;
    const float* src;
    ushortT* dst;
    size_t off;
    if (e < (size_t)(4u << 20)) { src = x; dst = xb; off = e; }
    else {
        const size_t r = e - (size_t)(4u << 20);
        const int wsel = (int)(r >> 20);
        off = r & 0xFFFFFu;
        src = (wsel == 0) ? Wq : (wsel == 1) ? Wk : (wsel == 2) ? Wv : Wo;
        dst = Wb + ((size_t)wsel << 20);
    }
    const float4 f0 = ((const float4*)(src + off))[0];
    const float4 f1 = ((const float4*)(src + off))[1];
    union { __hip_bfloat162 h[4]; uint4 u; } pk;
    pk.h[0] = __float22bfloat162_rn(float2{f0.x, f0.y});
    pk.h[1] = __float22bfloat162_rn(float2{f0.z, f0.w});
    pk.h[2] = __float22bfloat162_rn(float2{f1.x, f1.y});
    pk.h[3] = __float22bfloat162_rn(float2{f1.z, f1.w});
    *(uint4*)(dst + off) = pk.u;
}

// ---------------------------------------------------------------------------
// gemm_lds: C[m,n] = sum_k A[m,k]*W[n,k] + bias[n]. Pure bf16, global_load_lds
// staging with XOR chunk swizzle. 128x128 tile, BK=64, 4 waves, 4x4 MFMA.
// ---------------------------------------------------------------------------
template <bool OUT_F32>
__global__ __launch_bounds__(256) void gemm_lds(
    const ushortT* __restrict__ A, const ushortT* __restrict__ Wst,
    const float* __restrict__ b0, const float* __restrict__ b1, const float* __restrict__ b2,
    void* __restrict__ O0, void* __restrict__ O1, void* __restrict__ O2)
{
    __shared__ __align__(16) ushortT As[128 * 64];
    __shared__ __align__(16) ushortT Bs[128 * 64];
    const int t = threadIdx.x;
    const int m0 = blockIdx.y * 128;
    const int n0g = blockIdx.x * 128;
    const int mat = n0g >> 10;
    const int n0 = n0g & 1023;
    const ushortT* W = Wst + ((size_t)mat << 20);
    const float* bias = (mat == 0) ? b0 : (mat == 1) ? b1 : b2;
    void* Out        = (mat == 0) ? O0 : (mat == 1) ? O1 : O2;

    const int w = t >> 6, lane = t & 63;
    const int wm = w >> 1, wn = w & 1;
    const int col16 = lane & 15, quad = lane >> 4;

    floatx4 acc[4][4];
    for (int i = 0; i < 4; i++)
        for (int j = 0; j < 4; j++) acc[i][j] = (floatx4)0.0f;

    const int cid0 = w * 256 + lane;

    for (int k0 = 0; k0 < 1024; k0 += 64) {
        #pragma unroll
        for (int q = 0; q < 4; q++) {
            const int cid = cid0 + q * 64;
            const int row = cid >> 3;
            const int sch = (cid & 7) ^ (row & 7);
            ushortT* dstA = As + (size_t)(w * 256 + q * 64) * 8;
            ushortT* dstB = Bs + (size_t)(w * 256 + q * 64) * 8;
            gl_lds16(A + (size_t)(m0 + row) * 1024 + k0 + sch * 8, dstA);
            gl_lds16(W + (size_t)(n0 + row) * 1024 + k0 + sch * 8, dstB);
        }
        __syncthreads();
        #pragma unroll
        for (int ks = 0; ks < 64; ks += 32) {
            const int cbase = (ks >> 3) + quad;
            const int sw = col16 & 7;
            short8 a[4], b[4];
            #pragma unroll
            for (int i = 0; i < 4; i++) {
                const int row = wm * 64 + i * 16 + col16;
                a[i] = *(const short8*)(As + row * 64 + ((cbase ^ sw) << 3));
            }
            #pragma unroll
            for (int j = 0; j < 4; j++) {
                const int row = wn * 64 + j * 16 + col16;
                b[j] = *(const short8*)(Bs + row * 64 + ((cbase ^ sw) << 3));
            }
            #pragma unroll
            for (int i = 0; i < 4; i++)
                #pragma unroll
                for (int j = 0; j < 4; j++)
                    acc[i][j] = __builtin_amdgcn_mfma_f32_16x16x32_bf16(a[i], b[j], acc[i][j], 0, 0, 0);
        }
        __syncthreads();
    }

    for (int j = 0; j < 4; j++) {
        const int colg = n0 + wn * 64 + j * 16 + col16;
        const float bv = bias[colg];
        for (int i = 0; i < 4; i++) {
            const int rbase = m0 + wm * 64 + i * 16 + quad * 4;
            for (int r = 0; r < 4; r++) {
                const float val = acc[i][j][r] + bv;
                if constexpr (OUT_F32)
                    ((float*)Out)[(size_t)(rbase + r) * 1024 + colg] = val;
                else
                    ((ushortT*)Out)[(size_t)(rbase + r) * 1024 + colg] = f2bf(val);
            }
        }
    }
}

// ---------------------------------------------------------------------------
// transpose_v: Vb (packed rows) -> VT[slice][d (64)][pos (2048)], slice=(b*2+g)*8+m'.
// ---------------------------------------------------------------------------
__global__ __launch_bounds__(256) void transpose_v(
    const ushortT* __restrict__ Vb, ushortT* __restrict__ VT)
{
    __shared__ ushortT L[64 * 65];
    const int bid = blockIdx.x;
    const int pt = bid & 31, s = bid >> 5;
    const int bb = s >> 4, g = (s >> 3) & 1, mh = s & 7;
    const size_t baseoff = (size_t)bb * 2048 * 1024 + (size_t)g * 512;
    const int t = threadIdx.x;
    {
        const int pr = t >> 2, seg = t & 3;
        const int i = mh * 2048 + pt * 64 + pr;
        const uint4* src = (const uint4*)(Vb + baseoff + (size_t)(i >> 3) * 1024 + (i & 7) * 64 + seg * 16);
        union { uint4 u[2]; ushortT h[16]; } tmp;
        tmp.u[0] = src[0]; tmp.u[1] = src[1];
        #pragma unroll
        for (int d = 0; d < 16; d++) L[pr * 65 + seg * 16 + d] = tmp.h[d];
    }
    __syncthreads();
    {
        const int dc = t >> 2, pseg = t & 3;
        union { uint4 u[2]; ushortT h[16]; } tmp;
        #pragma unroll
        for (int j = 0; j < 16; j++) tmp.h[j] = L[(pseg * 16 + j) * 65 + dc];
        uint4* dst = (uint4*)(VT + (size_t)s * 64 * 2048 + (size_t)dc * 2048 + pt * 64 + pseg * 16);
        dst[0] = tmp.u[0]; dst[1] = tmp.u[1];
    }
}

// ---------------------------------------------------------------------------
// attn v4: transposed-softmax flash attention. Q fragments live in REGISTERS
// (constant over K-loop; B-operand layout needs only the lane's own query).
// LDS = Ks(2x8K) + Vs(2x8K) + Ps(8K) = 40 KB -> 4 blocks/CU (was 2).
// 512 blocks: xcd=bid&7 gets 4 whole slices; q-tiles qtA=p, qtB=31-p balanced.
// S^T = MFMA(A=K, B=Q) -> queries on col=lane&15; m/l/alpha per-lane scalar.
// O^T = MFMA(A=V^T, B=P^T). Ps pack via v_cvt_pk_bf16_f32 (was 4-op manual RNE).
// Cb may alias Qb (Q read at start, C written at end, same rows only).
// ---------------------------------------------------------------------------
__global__ __launch_bounds__(256) void attn(
    const ushortT* __restrict__ Qb, const ushortT* __restrict__ Kb,
    const ushortT* __restrict__ VT, ushortT* __restrict__ Cb)
{
    __shared__ __align__(16) ushortT Ks[2][64 * 64];   // [key][d], chunk-swizzled
    __shared__ __align__(16) ushortT Vs[2][64 * 64];   // [d][key], chunk-swizzled
    __shared__ __align__(16) ushortT Ps[64 * 64];      // [q][key], chunk-swizzled, per-wave rows

    const int t = threadIdx.x;
    const int bid = blockIdx.x;
    const int xcd = bid & 7;
    const int jj  = bid >> 3;
    const int s   = xcd * 4 + (jj >> 4);   // 4 slices per XCD
    const int p   = jj & 15;
    const int qtA = p, qtB = 31 - p;       // 33 compute-iters, balanced
    const int bb = s >> 4, g = (s >> 3) & 1, mh = s & 7;

    const int w = t >> 6, lane = t & 63;
    const int col16 = lane & 15, quad = lane >> 4;

    const size_t baseoff = (size_t)bb * 2048 * 1024 + (size_t)g * 512;
    const size_t vtbase  = (size_t)s * 64 * 2048;
    const int i0A = mh * 2048 + qtA * 64;
    const int i0B = mh * 2048 + qtB * 64;
    const int qloc = w * 16 + col16;       // this lane's query within a tile
    const int psw = qloc & 7;              // Ps chunk swizzle for this lane's row
    const float KL = 0.125f * 1.44269504f; // scale * log2(e)

    // Q fragments in registers: [tile][ks-half], B-operand layout.
    short8 qreg[2][2];
    {
        const int iA = i0A + qloc, iB = i0B + qloc;
        const ushortT* pA = Qb + baseoff + (size_t)(iA >> 3) * 1024 + (iA & 7) * 64;
        const ushortT* pB = Qb + baseoff + (size_t)(iB >> 3) * 1024 + (iB & 7) * 64;
        qreg[0][0] = *(const short8*)(pA + quad * 8);
        qreg[0][1] = *(const short8*)(pA + 32 + quad * 8);
        qreg[1][0] = *(const short8*)(pB + quad * 8);
        qreg[1][1] = *(const short8*)(pB + 32 + quad * 8);
    }

    auto stageKV = [&](int kt, int bsel) {
        ushortT* kd = &Ks[bsel][0] + (size_t)(w * 128) * 8;
        ushortT* vd = &Vs[bsel][0] + (size_t)(w * 128) * 8;
        #pragma unroll
        for (int q = 0; q < 2; q++) {
            const int cid = w * 128 + q * 64 + lane;
            const int row = cid >> 3;
            const int sch = (cid & 7) ^ (row & 7);
            const int jr = mh * 2048 + kt * 64 + row;
            gl_lds16(Kb + baseoff + (size_t)(jr >> 3) * 1024 + (jr & 7) * 64 + sch * 8,
                     kd + q * 64 * 8);
            gl_lds16(VT + vtbase + (size_t)row * 2048 + kt * 64 + sch * 8,
                     vd + q * 64 * 8);
        }
    };

    float m_s[2] = {-1e30f, -1e30f};
    float l_s[2] = {0.f, 0.f};
    floatx4 Oacc[2][4];
    for (int tl = 0; tl < 2; tl++)
        for (int c = 0; c < 4; c++) Oacc[tl][c] = (floatx4)0.0f;

    stageKV(0, 0);
    const int ktmax = qtB;
    for (int kt = 0; kt <= ktmax; ++kt) {
        const int bsel = kt & 1;
        __syncthreads();                            // vmcnt drained -> buffers ready
        if (kt < ktmax) stageKV(kt + 1, bsel ^ 1);  // prefetch overlaps compute

        #pragma unroll
        for (int tile = 0; tile < 2; ++tile) {
            const int qt = tile ? qtB : qtA;
            if (kt > qt) continue;                  // wave-uniform

            // S^T = K * Q^T : rows = keys, cols = queries
            floatx4 sc[4];
            for (int c = 0; c < 4; c++) sc[c] = (floatx4)0.0f;
            #pragma unroll
            for (int ks = 0; ks < 32 * 2; ks += 32) {
                const short8 bq = qreg[tile][ks >> 5];
                #pragma unroll
                for (int c = 0; c < 4; c++) {
                    const int krow = c * 16 + col16;
                    const short8 ak = *(const short8*)(&Ks[bsel][0] + krow * 64 +
                                        ((((ks >> 3) + quad) ^ (krow & 7)) << 3));
                    sc[c] = __builtin_amdgcn_mfma_f32_16x16x32_bf16(ak, bq, sc[c], 0, 0, 0);
                }
            }

            // online softmax: lane holds 16 keys of ONE query
            if (kt == qt) {                         // diagonal tile: causal mask
                #pragma unroll
                for (int c = 0; c < 4; c++)
                    #pragma unroll
                    for (int r = 0; r < 4; r++)
                        if ((c * 16 + quad * 4 + r) > qloc) sc[c][r] = -1e30f;
            }
            float mx = -1e30f;
            #pragma unroll
            for (int c = 0; c < 4; c++)
                #pragma unroll
                for (int r = 0; r < 4; r++) mx = fmaxf(mx, sc[c][r]);
            mx = fmaxf(mx, __shfl_xor(mx, 16));
            mx = fmaxf(mx, __shfl_xor(mx, 32));
            const float mold = m_s[tile];
            const float mnew = fmaxf(mold, mx);
            const float alpha = exp2f((mold - mnew) * KL);
            m_s[tile] = mnew;
            const float mKL = mnew * KL;
            float sum = 0.f;
            #pragma unroll
            for (int c = 0; c < 4; c++)
                #pragma unroll
                for (int r = 0; r < 4; r++) {
                    const float pv = exp2f(__builtin_fmaf(sc[c][r], KL, -mKL));
                    sc[c][r] = pv;
                    sum += pv;
                }
            sum += __shfl_xor(sum, 16);
            sum += __shfl_xor(sum, 32);
            l_s[tile] = l_s[tile] * alpha + sum;
            #pragma unroll
            for (int c = 0; c < 4; c++) Oacc[tile][c] *= alpha;

            // P -> Ps[q][key] via packed cvt; per-wave-private rows, no barrier.
            #pragma unroll
            for (int c = 0; c < 4; c++) {
                const int key0 = c * 16 + quad * 4;
                union { __hip_bfloat162 h[2]; unsigned long long u; } pk2;
                pk2.h[0] = __float22bfloat162_rn(float2{sc[c][0], sc[c][1]});
                pk2.h[1] = __float22bfloat162_rn(float2{sc[c][2], sc[c][3]});
                *(unsigned long long*)(Ps + qloc * 64 +
                    (((key0 >> 3) ^ psw) << 3) + (key0 & 7)) = pk2.u;
            }

            // O^T += V^T * P^T : rows = d, cols = queries
            #pragma unroll
            for (int kk = 0; kk < 32 * 2; kk += 32) {
                const short8 bp = *(const short8*)(Ps + qloc * 64 +
                                    ((((kk >> 3) + quad) ^ psw) << 3));
                #pragma unroll
                for (int c = 0; c < 4; c++) {
                    const int drow = c * 16 + col16;
                    const short8 av = *(const short8*)(&Vs[bsel][0] + drow * 64 +
                                        ((((kk >> 3) + quad) ^ (drow & 7)) << 3));
                    Oacc[tile][c] = __builtin_amdgcn_mfma_f32_16x16x32_bf16(av, bp, Oacc[tile][c], 0, 0, 0);
                }
            }
        }
    }

    // write ctx: lane owns query qloc of each tile; d = c*16 + quad*4 + r.
    #pragma unroll
    for (int tile = 0; tile < 2; ++tile) {
        const int i = (tile ? i0B : i0A) + qloc;
        const float inv = 1.0f / l_s[tile];
        ushortT* dst = Cb + baseoff + (size_t)(i >> 3) * 1024 + (i & 7) * 64;
        #pragma unroll
        for (int c = 0; c < 4; c++) {
            union { __hip_bfloat162 h[2]; unsigned long long u; } pk2;
            pk2.h[0] = __float22bfloat162_rn(float2{Oacc[tile][c][0] * inv, Oacc[tile][c][1] * inv});
            pk2.h[1] = __float22bfloat162_rn(float2{Oacc[tile][c][2] * inv, Oacc[tile][c][3] * inv});
            *(unsigned long long*)(dst + c * 16 + quad * 4) = pk2.u;
        }
    }
}

extern "C" void kernel_launch(void* const* d_in, const int* in_sizes, int n_in,
                              void* d_out, int out_size, void* d_ws, size_t ws_size,
                              hipStream_t stream)
{
    const float* x  = (const float*)d_in[0];
    const float* Wq = (const float*)d_in[1];
    const float* bq = (const float*)d_in[2];
    const float* Wk = (const float*)d_in[3];
    const float* bk = (const float*)d_in[4];
    const float* Wv = (const float*)d_in[5];
    const float* bv = (const float*)d_in[6];
    const float* Wo = (const float*)d_in[7];
    const float* bo = (const float*)d_in[8];

    const size_t M1 = (size_t)1024 * 1024;
    ushortT* Wb  = (ushortT*)d_ws;            // Wq|Wk|Wv|Wo bf16, 8 MB
    ushortT* xb  = Wb + 4 * M1;               // 8 MB; reused as VT after QKV
    ushortT* Qb  = xb + 4 * M1;               // 8 MB; reused as Cb
    ushortT* Kb  = Qb + 4 * M1;               // 8 MB
    ushortT* Vb  = (ushortT*)d_out;           // scratch in output buffer
    ushortT* VTb = xb;
    ushortT* Cb  = Qb;

    dim3 blk(256);
    cvt_bf16<<<dim3(4096), blk, 0, stream>>>(x, Wq, Wk, Wv, Wo, xb, Wb);
    gemm_lds<false><<<dim3(24, 32), blk, 0, stream>>>(
        xb, Wb, bq, bk, bv, Qb, Kb, Vb);
    transpose_v<<<dim3(1024), blk, 0, stream>>>(Vb, VTb);
    attn<<<dim3(512), blk, 0, stream>>>(Qb, Kb, VTb, Cb);
    gemm_lds<true><<<dim3(8, 32), blk, 0, stream>>>(
        Cb, Wb + 3 * M1, bo, bo, bo, d_out, d_out, d_out);
}